// Round 10
// baseline (1355.465 us; speedup 1.0000x reference)
//
#include <hip/hip_runtime.h>
#include <math.h>

#define N_NODES 100000
#define N_EDGES 1200000
#define GC 64
#define RBF 32
#define NLAYERS 4
#define NF 92
#define NATOM 100
#define BN_EPS 1e-5f
#define TILE_GRID 2048
#define NTILE_MAX 176000   // worst case N + E/16 = 175k

typedef _Float16 half8 __attribute__((ext_vector_type(8)));
typedef _Float16 half4 __attribute__((ext_vector_type(4)));
typedef _Float16 half2v __attribute__((ext_vector_type(2)));
typedef float f32x4 __attribute__((ext_vector_type(4)));
union U32H2 { unsigned int u; half2v h; };

// ---------- K1: degree histogram ----------
__global__ __launch_bounds__(256) void deg_kernel(
    const int* __restrict__ ei, int* __restrict__ deg)
{
    int e = blockIdx.x * 256 + threadIdx.x;
    if (e >= N_EDGES) return;
    atomicAdd(&deg[ei[N_EDGES + e]], 1);
}

// ---------- scan ----------
__global__ __launch_bounds__(256) void scan_a_kernel(const int* __restrict__ deg, int* __restrict__ bsums)
{
    __shared__ int sm[256];
    int tid = threadIdx.x;
    int i = blockIdx.x * 256 + tid;
    int v = (i < N_NODES) ? deg[i] : 0;
    sm[tid] = v;
    __syncthreads();
    for (int s = 128; s > 0; s >>= 1) {
        if (tid < s) sm[tid] += sm[tid + s];
        __syncthreads();
    }
    if (tid == 0) bsums[blockIdx.x] = sm[0];
}

__global__ __launch_bounds__(512) void scan_b_kernel(const int* __restrict__ bsums, int* __restrict__ boffs)
{
    __shared__ int sm[512];
    int tid = threadIdx.x;
    int v = (tid < 391) ? bsums[tid] : 0;
    sm[tid] = v;
    __syncthreads();
    for (int off = 1; off < 512; off <<= 1) {
        int t = (tid >= off) ? sm[tid - off] : 0;
        __syncthreads();
        sm[tid] += t;
        __syncthreads();
    }
    boffs[tid] = (tid == 0) ? 0 : sm[tid - 1];
}

// ---------- scan_c + tile_build fused: row_st, inv_deg, tile descriptors ----------
__global__ __launch_bounds__(256) void scan_c_kernel(
    const int* __restrict__ deg, const int* __restrict__ boffs,
    int* __restrict__ row_st, float* __restrict__ inv_deg,
    int2* __restrict__ tdesc, int* __restrict__ tcount)
{
    __shared__ int sm[256];
    int tid = threadIdx.x;
    int i = blockIdx.x * 256 + tid;
    int v = (i < N_NODES) ? deg[i] : 0;
    sm[tid] = v;
    __syncthreads();
    for (int off = 1; off < 256; off <<= 1) {
        int t = (tid >= off) ? sm[tid - off] : 0;
        __syncthreads();
        sm[tid] += t;
        __syncthreads();
    }
    int row = boffs[blockIdx.x] + sm[tid] - v;  // exclusive
    if (i <= N_NODES) row_st[i] = row;
    if (i < N_NODES) {
        inv_deg[i] = (v > 0) ? (1.0f / (float)v) : 0.0f;
        int tiles = (v + 15) >> 4;
        if (tiles > 0) {
            int base = atomicAdd(tcount, tiles);
            for (int t = 0; t < tiles; t++) {
                int cnt = v - 16 * t;
                if (cnt > 16) cnt = 16;
                tdesc[base + t] = make_int2(row + 16 * t, (i << 5) | cnt);
            }
        }
    }
}

// ---------- K2a: scatter edges into CSR order (dist only) ----------
__global__ __launch_bounds__(256) void scatter_kernel(
    const int* __restrict__ ei, const float* __restrict__ pos,
    const int* __restrict__ row_st, int* __restrict__ cursor,
    int* __restrict__ csr_src, float* __restrict__ csr_dist)
{
    int e = blockIdx.x * 256 + threadIdx.x;
    if (e >= N_EDGES) return;
    int s = ei[e];
    int d = ei[N_EDGES + e];
    float dx = pos[s * 3 + 0] - pos[d * 3 + 0];
    float dy = pos[s * 3 + 1] - pos[d * 3 + 1];
    float dz = pos[s * 3 + 2] - pos[d * 3 + 2];
    float dist = sqrtf(dx * dx + dy * dy + dz * dz + 1e-12f);
    int p = atomicAdd(&cursor[d], 1);
    int idx = row_st[d] + p;
    csr_src[idx] = s;
    csr_dist[idx] = dist;
}

// ---------- K2b: RBF features in CSR order (coalesced 64B writes) ----------
__global__ __launch_bounds__(256) void rbf_kernel(
    const float* __restrict__ csr_dist, const float* __restrict__ means,
    const float* __restrict__ betas, unsigned int* __restrict__ ea)
{
    int j = blockIdx.x * 256 + threadIdx.x;
    if (j >= N_EDGES) return;
    float dist = csr_dist[j];
    float cut = 0.0f;
    if (dist < 5.0f) cut = 0.5f * (__cosf(dist * 0.6283185307179586f) + 1.0f);
    float ex = __expf(-dist);
    union { _Float16 h[32]; uint4 u[4]; } pk;
#pragma unroll
    for (int k = 0; k < 32; k++) {
        float v = ex - means[k];
        pk.h[k] = (_Float16)(cut * __expf(-betas[k] * v * v));
    }
    uint4* op = (uint4*)(ea + (size_t)j * 16);
    op[0] = pk.u[0];
    op[1] = pk.u[1];
    op[2] = pk.u[2];
    op[3] = pk.u[3];
}

// ---------- K4a: per-atom-type pre-layer table ----------
__global__ __launch_bounds__(64) void atom_table_kernel(
    const float* __restrict__ emb, const float* __restrict__ pre_W,
    const float* __restrict__ pre_b, float* __restrict__ T)
{
    int a = blockIdx.x;
    int c = threadIdx.x;
    float acc = pre_b[c];
    for (int k = 0; k < NF; k++) acc = fmaf(emb[a * NF + k], pre_W[k * GC + c], acc);
    T[a * GC + c] = fmaxf(acc, 0.0f);
}

// ---------- K4b: broadcast table to nodes ----------
__global__ __launch_bounds__(256) void xinit_kernel(
    const int* __restrict__ atom_types, const float* __restrict__ T,
    float* __restrict__ x, _Float16* __restrict__ x16)
{
    int i = blockIdx.x * 256 + threadIdx.x;  // i < N*16
    int n = i >> 4;
    int a = atom_types[n];
    float4 v = ((const float4*)T)[a * 16 + (i & 15)];
    ((float4*)x)[i] = v;
    half4 h = { (_Float16)v.x, (_Float16)v.y, (_Float16)v.z, (_Float16)v.w };
    ((half4*)x16)[i] = h;
}

// ---------- shared MFMA proj body: P2[n][c] = {f,s} interleaved half2 ----------
static __device__ __forceinline__ void proj_mfma(
    const float* __restrict__ Wf, const float* __restrict__ Ws,
    const half8 Bn[2], int cb, int node, half2v* __restrict__ P2)
{
    half8 Af[2][2], As[2][2];
    const int lane = threadIdx.x & 63;
    const int quad = lane >> 4;
    const int r16 = lane & 15;
#pragma unroll
    for (int kt = 0; kt < 2; kt++) {
#pragma unroll
        for (int sub = 0; sub < 2; sub++) {
            int chan = cb + sub * 16 + r16;
            half8 a, b;
#pragma unroll
            for (int j = 0; j < 8; j++) {
                int k = kt * 32 + quad * 8 + j;
                a[j] = (_Float16)Wf[k * GC + chan];
                b[j] = (_Float16)Ws[k * GC + chan];
            }
            Af[kt][sub] = a;
            As[kt][sub] = b;
        }
    }
    f32x4 accf[2], accs[2];
#pragma unroll
    for (int sub = 0; sub < 2; sub++) {
        accf[sub] = (f32x4){0.f, 0.f, 0.f, 0.f};
        accs[sub] = (f32x4){0.f, 0.f, 0.f, 0.f};
    }
#pragma unroll
    for (int kt = 0; kt < 2; kt++) {
#pragma unroll
        for (int sub = 0; sub < 2; sub++) {
            accf[sub] = __builtin_amdgcn_mfma_f32_16x16x32_f16(Af[kt][sub], Bn[kt], accf[sub], 0, 0, 0);
            accs[sub] = __builtin_amdgcn_mfma_f32_16x16x32_f16(As[kt][sub], Bn[kt], accs[sub], 0, 0, 0);
        }
    }
#pragma unroll
    for (int sub = 0; sub < 2; sub++) {
        half8 h = { (_Float16)accf[sub][0], (_Float16)accs[sub][0],
                    (_Float16)accf[sub][1], (_Float16)accs[sub][1],
                    (_Float16)accf[sub][2], (_Float16)accs[sub][2],
                    (_Float16)accf[sub][3], (_Float16)accs[sub][3] };
        *(half8*)(P2 + (size_t)node * GC + cb + sub * 16 + quad * 4) = h;
    }
}

// ---------- K_proj0: standalone proj (layer 0) ----------
__global__ __launch_bounds__(256) void proj_kernel(
    const _Float16* __restrict__ x16,
    const float* __restrict__ Wf, const float* __restrict__ Ws,
    half2v* __restrict__ P2)
{
    const int lane = threadIdx.x & 63;
    const int wid = threadIdx.x >> 6;
    const int quad = lane >> 4;
    const int r16 = lane & 15;
    const int wgid = blockIdx.x * 4 + wid;
    const int cb = (wgid & 1) * 32;
    const int nb = (wgid >> 1) * 16;
    half8 Bn[2];
    Bn[0] = *(const half8*)(x16 + (size_t)(nb + r16) * GC + quad * 8);
    Bn[1] = *(const half8*)(x16 + (size_t)(nb + r16) * GC + 32 + quad * 8);
    proj_mfma(Wf, Ws, Bn, cb, nb + r16, P2);
}

// ---------- K_bnproj: BN apply (layer l) fused with proj (layer l+1) ----------
__global__ __launch_bounds__(256) void bnproj_kernel(
    const float* __restrict__ xn, const float* __restrict__ stats,
    const float* __restrict__ gamma, const float* __restrict__ beta,
    float* __restrict__ xout, _Float16* __restrict__ x16,
    const float* __restrict__ Wf, const float* __restrict__ Ws,  // next layer rows 0..63
    half2v* __restrict__ P2)
{
    __shared__ _Float16 lx[32 * 72];   // 72-half row pad -> 2-way (free) LDS banks
    const int nb = blockIdx.x * 32;
    const float invN = 1.0f / (float)N_NODES;

#pragma unroll
    for (int rep = 0; rep < 2; rep++) {
        int g = rep * 256 + threadIdx.x;        // granule within block: 0..511
        int gi = blockIdx.x * 512 + g;          // global float4 granule
        int node = g >> 4;                      // 0..31
        int c4 = (g & 15) * 4;
        float4 v = ((const float4*)xn)[gi];
        float vv[4] = {v.x, v.y, v.z, v.w};
        float o[4];
#pragma unroll
        for (int t = 0; t < 4; t++) {
            int c = c4 + t;
            float mu = stats[c] * invN;
            float var = stats[64 + c] * invN - mu * mu;
            float sc = gamma[c] * rsqrtf(var + BN_EPS);
            o[t] = (vv[t] - mu) * sc + beta[c];
        }
        ((float4*)xout)[gi] = make_float4(o[0], o[1], o[2], o[3]);
        half4 h = { (_Float16)o[0], (_Float16)o[1], (_Float16)o[2], (_Float16)o[3] };
        ((half4*)x16)[gi] = h;
        *(half4*)(lx + node * 72 + c4) = h;
    }
    __syncthreads();

    const int lane = threadIdx.x & 63;
    const int wid = threadIdx.x >> 6;
    const int quad = lane >> 4;
    const int r16 = lane & 15;
    const int cb = (wid & 1) * 32;
    const int tn = (wid >> 1) * 16 + r16;       // node within block's 32
    half8 Bn[2];
    Bn[0] = *(const half8*)(lx + tn * 72 + quad * 8);
    Bn[1] = *(const half8*)(lx + tn * 72 + 32 + quad * 8);
    proj_mfma(Wf, Ws, Bn, cb, nb + tn, P2);
}

// ---------- compute body for one tile ----------
static __device__ __forceinline__ void compute_tile(
    int n0, int c0, float inv0,
    half8 S0, half8 S1, half8 E, U32H2 P0, U32H2 P1,
    const half8 (&Bf)[3][2], const half8 (&Bs)[3][2],
    const float (&biasf)[2], const float (&biass)[2],
    int lane, int quad, int cb, float* __restrict__ x)
{
    f32x4 cf[2], cs[2];
    {
        float fi0 = (float)P0.h.x + biasf[0];
        float si0 = (float)P0.h.y + biass[0];
        float fi1 = (float)P1.h.x + biasf[1];
        float si1 = (float)P1.h.y + biass[1];
        cf[0] = (f32x4){fi0, fi0, fi0, fi0};
        cs[0] = (f32x4){si0, si0, si0, si0};
        cf[1] = (f32x4){fi1, fi1, fi1, fi1};
        cs[1] = (f32x4){si1, si1, si1, si1};
    }
#pragma unroll
    for (int ctl = 0; ctl < 2; ctl++) {
        cf[ctl] = __builtin_amdgcn_mfma_f32_16x16x32_f16(S0, Bf[0][ctl], cf[ctl], 0, 0, 0);
        cs[ctl] = __builtin_amdgcn_mfma_f32_16x16x32_f16(S0, Bs[0][ctl], cs[ctl], 0, 0, 0);
        cf[ctl] = __builtin_amdgcn_mfma_f32_16x16x32_f16(S1, Bf[1][ctl], cf[ctl], 0, 0, 0);
        cs[ctl] = __builtin_amdgcn_mfma_f32_16x16x32_f16(S1, Bs[1][ctl], cs[ctl], 0, 0, 0);
        cf[ctl] = __builtin_amdgcn_mfma_f32_16x16x32_f16(E,  Bf[2][ctl], cf[ctl], 0, 0, 0);
        cs[ctl] = __builtin_amdgcn_mfma_f32_16x16x32_f16(E,  Bs[2][ctl], cs[ctl], 0, 0, 0);
    }
    float acc0 = 0.0f, acc1 = 0.0f;
#pragma unroll
    for (int ctl = 0; ctl < 2; ctl++) {
#pragma unroll
        for (int rr = 0; rr < 4; rr++) {
            float af = cf[ctl][rr];
            float as = cs[ctl][rr];
            float sg = __builtin_amdgcn_rcpf(1.0f + __expf(-af));
            float sp = fmaxf(as, 0.0f) + __logf(1.0f + __expf(-fabsf(as)));
            float msg = (quad * 4 + rr < c0) ? sg * sp : 0.0f;
            if (ctl == 0) acc0 += msg; else acc1 += msg;
        }
    }
    acc0 += __shfl_xor(acc0, 16);
    acc0 += __shfl_xor(acc0, 32);
    acc1 += __shfl_xor(acc1, 16);
    acc1 += __shfl_xor(acc1, 32);
    if (lane < 32) {
        float a = (lane < 16) ? acc0 : acc1;
        atomicAdd(&x[(size_t)n0 * GC + cb + lane], a * inv0);
    }
}

// ---------- K5: flat-tile MFMA CGConv layer, 3-deep frag pipeline ----------
__global__ __launch_bounds__(256, 4) void tile_mfma_kernel(
    const _Float16* __restrict__ x16, const _Float16* __restrict__ ea,
    const int* __restrict__ csr_src, const int2* __restrict__ tdesc,
    const int* __restrict__ tcount, const float* __restrict__ inv_deg,
    const half2v* __restrict__ P2,
    const float* __restrict__ Wf, const float* __restrict__ Ws,   // [160][64]
    const float* __restrict__ bfv, const float* __restrict__ bsv, // [64]
    float* __restrict__ x)
{
    const int lane = threadIdx.x & 63;
    const int wid = threadIdx.x >> 6;
    const int quad = lane >> 4;
    const int r16 = lane & 15;

    const int wgid = blockIdx.x * 4 + wid;
    const int cthalf = wgid & 1;
    const int seq = wgid >> 1;
    const int NSEQ = TILE_GRID * 2;
    const int cb = cthalf * 32;

    half8 Bf[3][2], Bs[3][2];
#pragma unroll
    for (int kt = 0; kt < 3; kt++) {
#pragma unroll
        for (int ctl = 0; ctl < 2; ctl++) {
            int col = cb + ctl * 16 + r16;
            half8 bh, sh;
#pragma unroll
            for (int j = 0; j < 8; j++) {
                int k = 64 + kt * 32 + quad * 8 + j;
                bh[j] = (_Float16)Wf[k * GC + col];
                sh[j] = (_Float16)Ws[k * GC + col];
            }
            Bf[kt][ctl] = bh;
            Bs[kt][ctl] = sh;
        }
    }
    float biasf[2], biass[2];
#pragma unroll
    for (int ctl = 0; ctl < 2; ctl++) {
        int col = cb + ctl * 16 + r16;
        biasf[ctl] = bfv[col];
        biass[ctl] = bsv[col];
    }

    const int nt = tcount[0];
    if (seq >= nt) return;

    // ---- prologue: sets A/B/C = tiles T..T+2; meta for T+3; desc for T+4 ----
    int idx = seq;
    int2 d = tdesc[idx];
    int nA = d.y >> 5, cA = d.y & 31;
    float invA = inv_deg[nA];
    int jA = d.x + (r16 < cA ? r16 : cA - 1);
    int sA = csr_src[jA];

    int i1 = idx + NSEQ;
    d = tdesc[i1 < nt ? i1 : nt - 1];
    int nB = d.y >> 5, cB = d.y & 31;
    float invB = inv_deg[nB];
    int jB = d.x + (r16 < cB ? r16 : cB - 1);
    int sB = csr_src[jB];

    int i2 = i1 + NSEQ;
    d = tdesc[i2 < nt ? i2 : nt - 1];
    int nC = d.y >> 5, cC = d.y & 31;
    float invC = inv_deg[nC];
    int jC = d.x + (r16 < cC ? r16 : cC - 1);
    int sC = csr_src[jC];

    half8 AS0 = *(const half8*)(x16 + (size_t)sA * GC + quad * 8);
    half8 AS1 = *(const half8*)(x16 + (size_t)sA * GC + 32 + quad * 8);
    half8 AE  = *(const half8*)(ea + (size_t)jA * RBF + quad * 8);
    U32H2 AP0, AP1;
    AP0.u = *(const unsigned int*)(P2 + (size_t)nA * GC + cb + r16);
    AP1.u = *(const unsigned int*)(P2 + (size_t)nA * GC + cb + 16 + r16);

    half8 BS0 = *(const half8*)(x16 + (size_t)sB * GC + quad * 8);
    half8 BS1 = *(const half8*)(x16 + (size_t)sB * GC + 32 + quad * 8);
    half8 BE  = *(const half8*)(ea + (size_t)jB * RBF + quad * 8);
    U32H2 BP0, BP1;
    BP0.u = *(const unsigned int*)(P2 + (size_t)nB * GC + cb + r16);
    BP1.u = *(const unsigned int*)(P2 + (size_t)nB * GC + cb + 16 + r16);

    half8 CS0 = *(const half8*)(x16 + (size_t)sC * GC + quad * 8);
    half8 CS1 = *(const half8*)(x16 + (size_t)sC * GC + 32 + quad * 8);
    half8 CE  = *(const half8*)(ea + (size_t)jC * RBF + quad * 8);
    U32H2 CP0, CP1;
    CP0.u = *(const unsigned int*)(P2 + (size_t)nC * GC + cb + r16);
    CP1.u = *(const unsigned int*)(P2 + (size_t)nC * GC + cb + 16 + r16);

    int i3 = i2 + NSEQ;
    d = tdesc[i3 < nt ? i3 : nt - 1];
    int nN = d.y >> 5, cN = d.y & 31;
    float invN_ = inv_deg[nN];
    int jN = d.x + (r16 < cN ? r16 : cN - 1);
    int sN = csr_src[jN];

    int i4 = i3 + NSEQ;
    int2 dN = tdesc[i4 < nt ? i4 : nt - 1];

    while (true) {
        // ===== compute A, refill A <- T+3, advance meta/desc =====
        compute_tile(nA, cA, invA, AS0, AS1, AE, AP0, AP1,
                     Bf, Bs, biasf, biass, lane, quad, cb, x);
        AS0 = *(const half8*)(x16 + (size_t)sN * GC + quad * 8);
        AS1 = *(const half8*)(x16 + (size_t)sN * GC + 32 + quad * 8);
        AE  = *(const half8*)(ea + (size_t)jN * RBF + quad * 8);
        AP0.u = *(const unsigned int*)(P2 + (size_t)nN * GC + cb + r16);
        AP1.u = *(const unsigned int*)(P2 + (size_t)nN * GC + cb + 16 + r16);
        nA = nN; cA = cN; invA = invN_;
        nN = dN.y >> 5; cN = dN.y & 31;
        invN_ = inv_deg[nN];
        jN = dN.x + (r16 < cN ? r16 : cN - 1);
        sN = csr_src[jN];
        i4 += NSEQ;
        dN = tdesc[i4 < nt ? i4 : nt - 1];
        idx += NSEQ;
        if (idx >= nt) break;

        // ===== compute B =====
        compute_tile(nB, cB, invB, BS0, BS1, BE, BP0, BP1,
                     Bf, Bs, biasf, biass, lane, quad, cb, x);
        BS0 = *(const half8*)(x16 + (size_t)sN * GC + quad * 8);
        BS1 = *(const half8*)(x16 + (size_t)sN * GC + 32 + quad * 8);
        BE  = *(const half8*)(ea + (size_t)jN * RBF + quad * 8);
        BP0.u = *(const unsigned int*)(P2 + (size_t)nN * GC + cb + r16);
        BP1.u = *(const unsigned int*)(P2 + (size_t)nN * GC + cb + 16 + r16);
        nB = nN; cB = cN; invB = invN_;
        nN = dN.y >> 5; cN = dN.y & 31;
        invN_ = inv_deg[nN];
        jN = dN.x + (r16 < cN ? r16 : cN - 1);
        sN = csr_src[jN];
        i4 += NSEQ;
        dN = tdesc[i4 < nt ? i4 : nt - 1];
        idx += NSEQ;
        if (idx >= nt) break;

        // ===== compute C =====
        compute_tile(nC, cC, invC, CS0, CS1, CE, CP0, CP1,
                     Bf, Bs, biasf, biass, lane, quad, cb, x);
        CS0 = *(const half8*)(x16 + (size_t)sN * GC + quad * 8);
        CS1 = *(const half8*)(x16 + (size_t)sN * GC + 32 + quad * 8);
        CE  = *(const half8*)(ea + (size_t)jN * RBF + quad * 8);
        CP0.u = *(const unsigned int*)(P2 + (size_t)nN * GC + cb + r16);
        CP1.u = *(const unsigned int*)(P2 + (size_t)nN * GC + cb + 16 + r16);
        nC = nN; cC = cN; invC = invN_;
        nN = dN.y >> 5; cN = dN.y & 31;
        invN_ = inv_deg[nN];
        jN = dN.x + (r16 < cN ? r16 : cN - 1);
        sN = csr_src[jN];
        i4 += NSEQ;
        dN = tdesc[i4 < nt ? i4 : nt - 1];
        idx += NSEQ;
        if (idx >= nt) break;
    }
}

// ---------- K6: BN stats ----------
__global__ __launch_bounds__(256) void stats_kernel(const float* __restrict__ x, float* __restrict__ stats)
{
    const int lane = threadIdx.x & 63;
    const int wid = threadIdx.x >> 6;
    int w = blockIdx.x * 4 + wid;
    float s1 = 0.0f, s2 = 0.0f;
    for (int n = w; n < N_NODES; n += 1024) {
        float v = x[(size_t)n * GC + lane];
        s1 += v;
        s2 = fmaf(v, v, s2);
    }
    __shared__ float rs1[4][64];
    __shared__ float rs2[4][64];
    rs1[wid][lane] = s1;
    rs2[wid][lane] = s2;
    __syncthreads();
    if (threadIdx.x < 64) {
        atomicAdd(&stats[lane], rs1[0][lane] + rs1[1][lane] + rs1[2][lane] + rs1[3][lane]);
    } else if (threadIdx.x < 128) {
        int c = threadIdx.x & 63;
        atomicAdd(&stats[64 + c], rs2[0][c] + rs2[1][c] + rs2[2][c] + rs2[3][c]);
    }
}

// ---------- K7: final batchnorm apply (layer 3 -> d_out) ----------
__global__ __launch_bounds__(256) void bn_kernel(
    const float* __restrict__ xn, const float* __restrict__ stats,
    const float* __restrict__ gamma, const float* __restrict__ beta,
    float* __restrict__ out)
{
    int i = blockIdx.x * 256 + threadIdx.x;
    int c4 = (i & 15) * 4;
    float4 v = ((const float4*)xn)[i];
    float vv[4] = {v.x, v.y, v.z, v.w};
    float o[4];
    const float invN = 1.0f / (float)N_NODES;
#pragma unroll
    for (int t = 0; t < 4; t++) {
        int c = c4 + t;
        float mu = stats[c] * invN;
        float var = stats[64 + c] * invN - mu * mu;
        float sc = gamma[c] * rsqrtf(var + BN_EPS);
        o[t] = (vv[t] - mu) * sc + beta[c];
    }
    ((float4*)out)[i] = make_float4(o[0], o[1], o[2], o[3]);
}

extern "C" void kernel_launch(void* const* d_in, const int* in_sizes, int n_in,
                              void* d_out, int out_size, void* d_ws, size_t ws_size,
                              hipStream_t stream)
{
    const int* atom_types = (const int*)d_in[0];
    const float* pos = (const float*)d_in[1];
    const int* edge_index = (const int*)d_in[2];
    const float* emb = (const float*)d_in[3];
    const float* pre_W = (const float*)d_in[4];
    const float* pre_b = (const float*)d_in[5];
    const float* Wf = (const float*)d_in[6];
    const float* bf = (const float*)d_in[7];
    const float* Ws = (const float*)d_in[8];
    const float* bs = (const float*)d_in[9];
    const float* gamma = (const float*)d_in[10];
    const float* beta = (const float*)d_in[11];
    const float* means = (const float*)d_in[12];
    const float* betas = (const float*)d_in[13];

    char* base = (char*)d_ws;
    char* p = base;
    auto alloc = [&](size_t bytes) -> char* {
        char* r = p;
        p += (bytes + 255) & ~(size_t)255;
        return r;
    };
    unsigned int* ea = (unsigned int*)alloc((size_t)N_EDGES * RBF * 2);   // 76.8 MB fp16
    float* x = (float*)alloc((size_t)N_NODES * GC * 4);                   // 25.6 MB
    _Float16* x16 = (_Float16*)alloc((size_t)N_NODES * GC * 2);           // 12.8 MB
    half2v* P2 = (half2v*)alloc((size_t)N_NODES * GC * 4);                // 25.6 MB {f,s}
    int* csr_src = (int*)alloc((size_t)N_EDGES * 4);                      // 4.8 MB
    float* csr_dist = (float*)alloc((size_t)N_EDGES * 4);                 // 4.8 MB
    int2* tdesc = (int2*)alloc((size_t)NTILE_MAX * 8);                    // 1.4 MB
    int* row_st = (int*)alloc((size_t)(N_NODES + 1) * 4);
    float* inv_deg = (float*)alloc((size_t)N_NODES * 4);
    float* T = (float*)alloc((size_t)NATOM * GC * 4);
    int* bsums = (int*)alloc(512 * 4);
    int* boffs = (int*)alloc(512 * 4);
    const size_t ZR_INTS = (size_t)2 * N_NODES + 128 * NLAYERS + 64;
    char* zr = alloc(ZR_INTS * 4);
    int* deg = (int*)zr;
    int* cursor = deg + N_NODES;
    float* stats = (float*)(cursor + N_NODES);
    int* tcount = (int*)(stats + 128 * NLAYERS);

    if ((size_t)(p - base) > ws_size) return;  // diagnostic bail

    hipMemsetAsync(zr, 0, ZR_INTS * 4, stream);

    const int EG = (N_EDGES + 255) / 256;
    deg_kernel<<<EG, 256, 0, stream>>>(edge_index, deg);
    scan_a_kernel<<<391, 256, 0, stream>>>(deg, bsums);
    scan_b_kernel<<<1, 512, 0, stream>>>(bsums, boffs);
    scan_c_kernel<<<391, 256, 0, stream>>>(deg, boffs, row_st, inv_deg, tdesc, tcount);
    scatter_kernel<<<EG, 256, 0, stream>>>(edge_index, pos, row_st, cursor, csr_src, csr_dist);
    rbf_kernel<<<EG, 256, 0, stream>>>(csr_dist, means, betas, ea);
    atom_table_kernel<<<NATOM, 64, 0, stream>>>(emb, pre_W, pre_b, T);
    xinit_kernel<<<N_NODES * 16 / 256, 256, 0, stream>>>(atom_types, T, x, x16);
    proj_kernel<<<N_NODES / 32, 256, 0, stream>>>(x16, Wf, Ws, P2);

    for (int l = 0; l < NLAYERS; l++) {
        const float* Wfl = Wf + (size_t)l * 160 * GC;
        const float* Wsl = Ws + (size_t)l * 160 * GC;
        tile_mfma_kernel<<<TILE_GRID, 256, 0, stream>>>(
            x16, (const _Float16*)ea, csr_src, tdesc, tcount, inv_deg, P2,
            Wfl, Wsl, bf + l * GC, bs + l * GC, x);
        stats_kernel<<<256, 256, 0, stream>>>(x, stats + l * 128);
        if (l < NLAYERS - 1) {
            bnproj_kernel<<<N_NODES / 32, 256, 0, stream>>>(
                x, stats + l * 128, gamma + l * GC, beta + l * GC,
                x, x16, Wfl + 160 * GC, Wsl + 160 * GC, P2);
        } else {
            bn_kernel<<<N_NODES * 16 / 256, 256, 0, stream>>>(
                x, stats + l * 128, gamma + l * GC, beta + l * GC, (float*)d_out);
        }
    }
}

// Round 11
// 951.787 us; speedup vs baseline: 1.4241x; 1.4241x over previous
//
#include <hip/hip_runtime.h>
#include <math.h>

#define N_NODES 100000
#define N_EDGES 1200000
#define GC 64
#define RBF 32
#define NLAYERS 4
#define NF 92
#define NATOM 100
#define BN_EPS 1e-5f
#define TILE_GRID 2048
#define NTILE_MAX 176000   // worst case N + E/16 = 175k

typedef _Float16 half8 __attribute__((ext_vector_type(8)));
typedef _Float16 half4 __attribute__((ext_vector_type(4)));
typedef _Float16 half2v __attribute__((ext_vector_type(2)));
typedef float f32x4 __attribute__((ext_vector_type(4)));
union U32H2 { unsigned int u; half2v h; };

// ---------- K1: degree histogram ----------
__global__ __launch_bounds__(256) void deg_kernel(
    const int* __restrict__ ei, int* __restrict__ deg)
{
    int e = blockIdx.x * 256 + threadIdx.x;
    if (e >= N_EDGES) return;
    atomicAdd(&deg[ei[N_EDGES + e]], 1);
}

// ---------- scan ----------
__global__ __launch_bounds__(256) void scan_a_kernel(const int* __restrict__ deg, int* __restrict__ bsums)
{
    __shared__ int sm[256];
    int tid = threadIdx.x;
    int i = blockIdx.x * 256 + tid;
    int v = (i < N_NODES) ? deg[i] : 0;
    sm[tid] = v;
    __syncthreads();
    for (int s = 128; s > 0; s >>= 1) {
        if (tid < s) sm[tid] += sm[tid + s];
        __syncthreads();
    }
    if (tid == 0) bsums[blockIdx.x] = sm[0];
}

__global__ __launch_bounds__(512) void scan_b_kernel(const int* __restrict__ bsums, int* __restrict__ boffs)
{
    __shared__ int sm[512];
    int tid = threadIdx.x;
    int v = (tid < 391) ? bsums[tid] : 0;
    sm[tid] = v;
    __syncthreads();
    for (int off = 1; off < 512; off <<= 1) {
        int t = (tid >= off) ? sm[tid - off] : 0;
        __syncthreads();
        sm[tid] += t;
        __syncthreads();
    }
    boffs[tid] = (tid == 0) ? 0 : sm[tid - 1];
}

// ---------- scan_c + tile_build fused ----------
__global__ __launch_bounds__(256) void scan_c_kernel(
    const int* __restrict__ deg, const int* __restrict__ boffs,
    int* __restrict__ row_st, float* __restrict__ inv_deg,
    int2* __restrict__ tdesc, int* __restrict__ tcount)
{
    __shared__ int sm[256];
    int tid = threadIdx.x;
    int i = blockIdx.x * 256 + tid;
    int v = (i < N_NODES) ? deg[i] : 0;
    sm[tid] = v;
    __syncthreads();
    for (int off = 1; off < 256; off <<= 1) {
        int t = (tid >= off) ? sm[tid - off] : 0;
        __syncthreads();
        sm[tid] += t;
        __syncthreads();
    }
    int row = boffs[blockIdx.x] + sm[tid] - v;  // exclusive
    if (i <= N_NODES) row_st[i] = row;
    if (i < N_NODES) {
        inv_deg[i] = (v > 0) ? (1.0f / (float)v) : 0.0f;
        int tiles = (v + 15) >> 4;
        if (tiles > 0) {
            int base = atomicAdd(tcount, tiles);
            for (int t = 0; t < tiles; t++) {
                int cnt = v - 16 * t;
                if (cnt > 16) cnt = 16;
                tdesc[base + t] = make_int2(row + 16 * t, (i << 5) | cnt);
            }
        }
    }
}

// ---------- K2a: scatter edges into CSR order (dist only) ----------
__global__ __launch_bounds__(256) void scatter_kernel(
    const int* __restrict__ ei, const float* __restrict__ pos,
    const int* __restrict__ row_st, int* __restrict__ cursor,
    int* __restrict__ csr_src, float* __restrict__ csr_dist)
{
    int e = blockIdx.x * 256 + threadIdx.x;
    if (e >= N_EDGES) return;
    int s = ei[e];
    int d = ei[N_EDGES + e];
    float dx = pos[s * 3 + 0] - pos[d * 3 + 0];
    float dy = pos[s * 3 + 1] - pos[d * 3 + 1];
    float dz = pos[s * 3 + 2] - pos[d * 3 + 2];
    float dist = sqrtf(dx * dx + dy * dy + dz * dz + 1e-12f);
    int p = atomicAdd(&cursor[d], 1);
    int idx = row_st[d] + p;
    csr_src[idx] = s;
    csr_dist[idx] = dist;
}

// ---------- K2b: RBF features in CSR order (coalesced 64B writes) ----------
__global__ __launch_bounds__(256) void rbf_kernel(
    const float* __restrict__ csr_dist, const float* __restrict__ means,
    const float* __restrict__ betas, unsigned int* __restrict__ ea)
{
    int j = blockIdx.x * 256 + threadIdx.x;
    if (j >= N_EDGES) return;
    float dist = csr_dist[j];
    float cut = 0.0f;
    if (dist < 5.0f) cut = 0.5f * (__cosf(dist * 0.6283185307179586f) + 1.0f);
    float ex = __expf(-dist);
    union { _Float16 h[32]; uint4 u[4]; } pk;
#pragma unroll
    for (int k = 0; k < 32; k++) {
        float v = ex - means[k];
        pk.h[k] = (_Float16)(cut * __expf(-betas[k] * v * v));
    }
    uint4* op = (uint4*)(ea + (size_t)j * 16);
    op[0] = pk.u[0];
    op[1] = pk.u[1];
    op[2] = pk.u[2];
    op[3] = pk.u[3];
}

// ---------- K4a: per-atom-type pre-layer table ----------
__global__ __launch_bounds__(64) void atom_table_kernel(
    const float* __restrict__ emb, const float* __restrict__ pre_W,
    const float* __restrict__ pre_b, float* __restrict__ T)
{
    int a = blockIdx.x;
    int c = threadIdx.x;
    float acc = pre_b[c];
    for (int k = 0; k < NF; k++) acc = fmaf(emb[a * NF + k], pre_W[k * GC + c], acc);
    T[a * GC + c] = fmaxf(acc, 0.0f);
}

// ---------- K4b: broadcast table to nodes ----------
__global__ __launch_bounds__(256) void xinit_kernel(
    const int* __restrict__ atom_types, const float* __restrict__ T,
    float* __restrict__ x, _Float16* __restrict__ x16)
{
    int i = blockIdx.x * 256 + threadIdx.x;  // i < N*16
    int n = i >> 4;
    int a = atom_types[n];
    float4 v = ((const float4*)T)[a * 16 + (i & 15)];
    ((float4*)x)[i] = v;
    half4 h = { (_Float16)v.x, (_Float16)v.y, (_Float16)v.z, (_Float16)v.w };
    ((half4*)x16)[i] = h;
}

// ---------- shared MFMA proj body: P2[n][c] = {f,s} interleaved half2 ----------
static __device__ __forceinline__ void proj_mfma(
    const float* __restrict__ Wf, const float* __restrict__ Ws,
    const half8 Bn[2], int cb, int node, half2v* __restrict__ P2)
{
    half8 Af[2][2], As[2][2];
    const int lane = threadIdx.x & 63;
    const int quad = lane >> 4;
    const int r16 = lane & 15;
#pragma unroll
    for (int kt = 0; kt < 2; kt++) {
#pragma unroll
        for (int sub = 0; sub < 2; sub++) {
            int chan = cb + sub * 16 + r16;
            half8 a, b;
#pragma unroll
            for (int j = 0; j < 8; j++) {
                int k = kt * 32 + quad * 8 + j;
                a[j] = (_Float16)Wf[k * GC + chan];
                b[j] = (_Float16)Ws[k * GC + chan];
            }
            Af[kt][sub] = a;
            As[kt][sub] = b;
        }
    }
    f32x4 accf[2], accs[2];
#pragma unroll
    for (int sub = 0; sub < 2; sub++) {
        accf[sub] = (f32x4){0.f, 0.f, 0.f, 0.f};
        accs[sub] = (f32x4){0.f, 0.f, 0.f, 0.f};
    }
#pragma unroll
    for (int kt = 0; kt < 2; kt++) {
#pragma unroll
        for (int sub = 0; sub < 2; sub++) {
            accf[sub] = __builtin_amdgcn_mfma_f32_16x16x32_f16(Af[kt][sub], Bn[kt], accf[sub], 0, 0, 0);
            accs[sub] = __builtin_amdgcn_mfma_f32_16x16x32_f16(As[kt][sub], Bn[kt], accs[sub], 0, 0, 0);
        }
    }
#pragma unroll
    for (int sub = 0; sub < 2; sub++) {
        half8 h = { (_Float16)accf[sub][0], (_Float16)accs[sub][0],
                    (_Float16)accf[sub][1], (_Float16)accs[sub][1],
                    (_Float16)accf[sub][2], (_Float16)accs[sub][2],
                    (_Float16)accf[sub][3], (_Float16)accs[sub][3] };
        *(half8*)(P2 + (size_t)node * GC + cb + sub * 16 + quad * 4) = h;
    }
}

// ---------- K_proj0: standalone proj (layer 0) ----------
__global__ __launch_bounds__(256) void proj_kernel(
    const _Float16* __restrict__ x16,
    const float* __restrict__ Wf, const float* __restrict__ Ws,
    half2v* __restrict__ P2)
{
    const int lane = threadIdx.x & 63;
    const int wid = threadIdx.x >> 6;
    const int quad = lane >> 4;
    const int r16 = lane & 15;
    const int wgid = blockIdx.x * 4 + wid;
    const int cb = (wgid & 1) * 32;
    const int nb = (wgid >> 1) * 16;
    half8 Bn[2];
    Bn[0] = *(const half8*)(x16 + (size_t)(nb + r16) * GC + quad * 8);
    Bn[1] = *(const half8*)(x16 + (size_t)(nb + r16) * GC + 32 + quad * 8);
    proj_mfma(Wf, Ws, Bn, cb, nb + r16, P2);
}

// ---------- K_bnproj: BN apply (layer l) fused with proj (layer l+1) ----------
__global__ __launch_bounds__(256) void bnproj_kernel(
    const float* __restrict__ xn, const float* __restrict__ stats,
    const float* __restrict__ gamma, const float* __restrict__ beta,
    float* __restrict__ xout, _Float16* __restrict__ x16,
    const float* __restrict__ Wf, const float* __restrict__ Ws,  // next layer rows 0..63
    half2v* __restrict__ P2)
{
    __shared__ _Float16 lx[32 * 72];   // 72-half row pad -> 2-way (free) LDS banks
    const int nb = blockIdx.x * 32;
    const float invN = 1.0f / (float)N_NODES;

#pragma unroll
    for (int rep = 0; rep < 2; rep++) {
        int g = rep * 256 + threadIdx.x;        // granule within block: 0..511
        int gi = blockIdx.x * 512 + g;          // global float4 granule
        int node = g >> 4;                      // 0..31
        int c4 = (g & 15) * 4;
        float4 v = ((const float4*)xn)[gi];
        float vv[4] = {v.x, v.y, v.z, v.w};
        float o[4];
#pragma unroll
        for (int t = 0; t < 4; t++) {
            int c = c4 + t;
            float mu = stats[c] * invN;
            float var = stats[64 + c] * invN - mu * mu;
            float sc = gamma[c] * rsqrtf(var + BN_EPS);
            o[t] = (vv[t] - mu) * sc + beta[c];
        }
        ((float4*)xout)[gi] = make_float4(o[0], o[1], o[2], o[3]);
        half4 h = { (_Float16)o[0], (_Float16)o[1], (_Float16)o[2], (_Float16)o[3] };
        ((half4*)x16)[gi] = h;
        *(half4*)(lx + node * 72 + c4) = h;
    }
    __syncthreads();

    const int lane = threadIdx.x & 63;
    const int wid = threadIdx.x >> 6;
    const int quad = lane >> 4;
    const int r16 = lane & 15;
    const int cb = (wid & 1) * 32;
    const int tn = (wid >> 1) * 16 + r16;       // node within block's 32
    half8 Bn[2];
    Bn[0] = *(const half8*)(lx + tn * 72 + quad * 8);
    Bn[1] = *(const half8*)(lx + tn * 72 + 32 + quad * 8);
    proj_mfma(Wf, Ws, Bn, cb, nb + tn, P2);
}

// ---------- compute body for one tile ----------
static __device__ __forceinline__ void compute_tile(
    int n0, int c0, float inv0,
    half8 S0, half8 S1, half8 E, U32H2 P0, U32H2 P1,
    const half8 (&Bf)[3][2], const half8 (&Bs)[3][2],
    const float (&biasf)[2], const float (&biass)[2],
    int lane, int quad, int cb, float* __restrict__ x)
{
    f32x4 cf[2], cs[2];
    {
        float fi0 = (float)P0.h.x + biasf[0];
        float si0 = (float)P0.h.y + biass[0];
        float fi1 = (float)P1.h.x + biasf[1];
        float si1 = (float)P1.h.y + biass[1];
        cf[0] = (f32x4){fi0, fi0, fi0, fi0};
        cs[0] = (f32x4){si0, si0, si0, si0};
        cf[1] = (f32x4){fi1, fi1, fi1, fi1};
        cs[1] = (f32x4){si1, si1, si1, si1};
    }
#pragma unroll
    for (int ctl = 0; ctl < 2; ctl++) {
        cf[ctl] = __builtin_amdgcn_mfma_f32_16x16x32_f16(S0, Bf[0][ctl], cf[ctl], 0, 0, 0);
        cs[ctl] = __builtin_amdgcn_mfma_f32_16x16x32_f16(S0, Bs[0][ctl], cs[ctl], 0, 0, 0);
        cf[ctl] = __builtin_amdgcn_mfma_f32_16x16x32_f16(S1, Bf[1][ctl], cf[ctl], 0, 0, 0);
        cs[ctl] = __builtin_amdgcn_mfma_f32_16x16x32_f16(S1, Bs[1][ctl], cs[ctl], 0, 0, 0);
        cf[ctl] = __builtin_amdgcn_mfma_f32_16x16x32_f16(E,  Bf[2][ctl], cf[ctl], 0, 0, 0);
        cs[ctl] = __builtin_amdgcn_mfma_f32_16x16x32_f16(E,  Bs[2][ctl], cs[ctl], 0, 0, 0);
    }
    float acc0 = 0.0f, acc1 = 0.0f;
#pragma unroll
    for (int ctl = 0; ctl < 2; ctl++) {
#pragma unroll
        for (int rr = 0; rr < 4; rr++) {
            float af = cf[ctl][rr];
            float as = cs[ctl][rr];
            float sg = __builtin_amdgcn_rcpf(1.0f + __expf(-af));
            float sp = fmaxf(as, 0.0f) + __logf(1.0f + __expf(-fabsf(as)));
            float msg = (quad * 4 + rr < c0) ? sg * sp : 0.0f;
            if (ctl == 0) acc0 += msg; else acc1 += msg;
        }
    }
    acc0 += __shfl_xor(acc0, 16);
    acc0 += __shfl_xor(acc0, 32);
    acc1 += __shfl_xor(acc1, 16);
    acc1 += __shfl_xor(acc1, 32);
    if (lane < 32) {
        float a = (lane < 16) ? acc0 : acc1;
        atomicAdd(&x[(size_t)n0 * GC + cb + lane], a * inv0);
    }
}

// ---------- K5: flat-tile MFMA CGConv layer, 2-deep frag pipeline (round-9 proven) ----------
__global__ __launch_bounds__(256, 4) void tile_mfma_kernel(
    const _Float16* __restrict__ x16, const _Float16* __restrict__ ea,
    const int* __restrict__ csr_src, const int2* __restrict__ tdesc,
    const int* __restrict__ tcount, const float* __restrict__ inv_deg,
    const half2v* __restrict__ P2,
    const float* __restrict__ Wf, const float* __restrict__ Ws,   // [160][64]
    const float* __restrict__ bfv, const float* __restrict__ bsv, // [64]
    float* __restrict__ x)
{
    const int lane = threadIdx.x & 63;
    const int wid = threadIdx.x >> 6;
    const int quad = lane >> 4;
    const int r16 = lane & 15;

    const int wgid = blockIdx.x * 4 + wid;
    const int cthalf = wgid & 1;
    const int seq = wgid >> 1;
    const int NSEQ = TILE_GRID * 2;
    const int cb = cthalf * 32;

    half8 Bf[3][2], Bs[3][2];
#pragma unroll
    for (int kt = 0; kt < 3; kt++) {
#pragma unroll
        for (int ctl = 0; ctl < 2; ctl++) {
            int col = cb + ctl * 16 + r16;
            half8 bh, sh;
#pragma unroll
            for (int j = 0; j < 8; j++) {
                int k = 64 + kt * 32 + quad * 8 + j;
                bh[j] = (_Float16)Wf[k * GC + col];
                sh[j] = (_Float16)Ws[k * GC + col];
            }
            Bf[kt][ctl] = bh;
            Bs[kt][ctl] = sh;
        }
    }
    float biasf[2], biass[2];
#pragma unroll
    for (int ctl = 0; ctl < 2; ctl++) {
        int col = cb + ctl * 16 + r16;
        biasf[ctl] = bfv[col];
        biass[ctl] = bsv[col];
    }

    const int nt = tcount[0];
    if (seq >= nt) return;

    // ---- prologue: set A = tile T, set B = tile T+1, stage2 = T+2, desc3 = T+3 ----
    int idx = seq;
    int2 d = tdesc[idx];
    int nA = d.y >> 5, cA = d.y & 31;
    float invA = inv_deg[nA];
    int jA = d.x + (r16 < cA ? r16 : cA - 1);
    int sA = csr_src[jA];
    half8 AS0 = *(const half8*)(x16 + (size_t)sA * GC + quad * 8);
    half8 AS1 = *(const half8*)(x16 + (size_t)sA * GC + 32 + quad * 8);
    half8 AE  = *(const half8*)(ea + (size_t)jA * RBF + quad * 8);
    U32H2 AP0, AP1;
    AP0.u = *(const unsigned int*)(P2 + (size_t)nA * GC + cb + r16);
    AP1.u = *(const unsigned int*)(P2 + (size_t)nA * GC + cb + 16 + r16);

    int idx1 = idx + NSEQ;
    d = tdesc[idx1 < nt ? idx1 : nt - 1];
    int nB = d.y >> 5, cB = d.y & 31;
    float invB = inv_deg[nB];
    int jB = d.x + (r16 < cB ? r16 : cB - 1);
    int sB = csr_src[jB];
    half8 BS0 = *(const half8*)(x16 + (size_t)sB * GC + quad * 8);
    half8 BS1 = *(const half8*)(x16 + (size_t)sB * GC + 32 + quad * 8);
    half8 BE  = *(const half8*)(ea + (size_t)jB * RBF + quad * 8);
    U32H2 BP0, BP1;
    BP0.u = *(const unsigned int*)(P2 + (size_t)nB * GC + cb + r16);
    BP1.u = *(const unsigned int*)(P2 + (size_t)nB * GC + cb + 16 + r16);

    int idx2 = idx1 + NSEQ;
    d = tdesc[idx2 < nt ? idx2 : nt - 1];
    int n2 = d.y >> 5, c2 = d.y & 31;
    float inv2 = inv_deg[n2];
    int j2 = d.x + (r16 < c2 ? r16 : c2 - 1);
    int s2 = csr_src[j2];

    int idx3 = idx2 + NSEQ;
    int2 d3 = tdesc[idx3 < nt ? idx3 : nt - 1];

    while (true) {
        // ===== compute tile (set A) =====
        compute_tile(nA, cA, invA, AS0, AS1, AE, AP0, AP1,
                     Bf, Bs, biasf, biass, lane, quad, cb, x);
        AS0 = *(const half8*)(x16 + (size_t)s2 * GC + quad * 8);
        AS1 = *(const half8*)(x16 + (size_t)s2 * GC + 32 + quad * 8);
        AE  = *(const half8*)(ea + (size_t)j2 * RBF + quad * 8);
        AP0.u = *(const unsigned int*)(P2 + (size_t)n2 * GC + cb + r16);
        AP1.u = *(const unsigned int*)(P2 + (size_t)n2 * GC + cb + 16 + r16);
        nA = n2; cA = c2; invA = inv2;
        n2 = d3.y >> 5; c2 = d3.y & 31;
        inv2 = inv_deg[n2];
        j2 = d3.x + (r16 < c2 ? r16 : c2 - 1);
        s2 = csr_src[j2];
        idx3 += NSEQ;
        d3 = tdesc[idx3 < nt ? idx3 : nt - 1];

        idx += NSEQ;
        if (idx >= nt) break;

        // ===== compute tile (set B) =====
        compute_tile(nB, cB, invB, BS0, BS1, BE, BP0, BP1,
                     Bf, Bs, biasf, biass, lane, quad, cb, x);
        BS0 = *(const half8*)(x16 + (size_t)s2 * GC + quad * 8);
        BS1 = *(const half8*)(x16 + (size_t)s2 * GC + 32 + quad * 8);
        BE  = *(const half8*)(ea + (size_t)j2 * RBF + quad * 8);
        BP0.u = *(const unsigned int*)(P2 + (size_t)n2 * GC + cb + r16);
        BP1.u = *(const unsigned int*)(P2 + (size_t)n2 * GC + cb + 16 + r16);
        nB = n2; cB = c2; invB = inv2;
        n2 = d3.y >> 5; c2 = d3.y & 31;
        inv2 = inv_deg[n2];
        j2 = d3.x + (r16 < c2 ? r16 : c2 - 1);
        s2 = csr_src[j2];
        idx3 += NSEQ;
        d3 = tdesc[idx3 < nt ? idx3 : nt - 1];

        idx += NSEQ;
        if (idx >= nt) break;
    }
}

// ---------- K6: BN stats ----------
__global__ __launch_bounds__(256) void stats_kernel(const float* __restrict__ x, float* __restrict__ stats)
{
    const int lane = threadIdx.x & 63;
    const int wid = threadIdx.x >> 6;
    int w = blockIdx.x * 4 + wid;
    float s1 = 0.0f, s2 = 0.0f;
    for (int n = w; n < N_NODES; n += 1024) {
        float v = x[(size_t)n * GC + lane];
        s1 += v;
        s2 = fmaf(v, v, s2);
    }
    __shared__ float rs1[4][64];
    __shared__ float rs2[4][64];
    rs1[wid][lane] = s1;
    rs2[wid][lane] = s2;
    __syncthreads();
    if (threadIdx.x < 64) {
        atomicAdd(&stats[lane], rs1[0][lane] + rs1[1][lane] + rs1[2][lane] + rs1[3][lane]);
    } else if (threadIdx.x < 128) {
        int c = threadIdx.x & 63;
        atomicAdd(&stats[64 + c], rs2[0][c] + rs2[1][c] + rs2[2][c] + rs2[3][c]);
    }
}

// ---------- K7: final batchnorm apply (layer 3 -> d_out) ----------
__global__ __launch_bounds__(256) void bn_kernel(
    const float* __restrict__ xn, const float* __restrict__ stats,
    const float* __restrict__ gamma, const float* __restrict__ beta,
    float* __restrict__ out)
{
    int i = blockIdx.x * 256 + threadIdx.x;
    int c4 = (i & 15) * 4;
    float4 v = ((const float4*)xn)[i];
    float vv[4] = {v.x, v.y, v.z, v.w};
    float o[4];
    const float invN = 1.0f / (float)N_NODES;
#pragma unroll
    for (int t = 0; t < 4; t++) {
        int c = c4 + t;
        float mu = stats[c] * invN;
        float var = stats[64 + c] * invN - mu * mu;
        float sc = gamma[c] * rsqrtf(var + BN_EPS);
        o[t] = (vv[t] - mu) * sc + beta[c];
    }
    ((float4*)out)[i] = make_float4(o[0], o[1], o[2], o[3]);
}

extern "C" void kernel_launch(void* const* d_in, const int* in_sizes, int n_in,
                              void* d_out, int out_size, void* d_ws, size_t ws_size,
                              hipStream_t stream)
{
    const int* atom_types = (const int*)d_in[0];
    const float* pos = (const float*)d_in[1];
    const int* edge_index = (const int*)d_in[2];
    const float* emb = (const float*)d_in[3];
    const float* pre_W = (const float*)d_in[4];
    const float* pre_b = (const float*)d_in[5];
    const float* Wf = (const float*)d_in[6];
    const float* bf = (const float*)d_in[7];
    const float* Ws = (const float*)d_in[8];
    const float* bs = (const float*)d_in[9];
    const float* gamma = (const float*)d_in[10];
    const float* beta = (const float*)d_in[11];
    const float* means = (const float*)d_in[12];
    const float* betas = (const float*)d_in[13];

    char* base = (char*)d_ws;
    char* p = base;
    auto alloc = [&](size_t bytes) -> char* {
        char* r = p;
        p += (bytes + 255) & ~(size_t)255;
        return r;
    };
    unsigned int* ea = (unsigned int*)alloc((size_t)N_EDGES * RBF * 2);   // 76.8 MB fp16
    float* x = (float*)alloc((size_t)N_NODES * GC * 4);                   // 25.6 MB
    _Float16* x16 = (_Float16*)alloc((size_t)N_NODES * GC * 2);           // 12.8 MB
    half2v* P2 = (half2v*)alloc((size_t)N_NODES * GC * 4);                // 25.6 MB {f,s}
    int* csr_src = (int*)alloc((size_t)N_EDGES * 4);                      // 4.8 MB
    float* csr_dist = (float*)alloc((size_t)N_EDGES * 4);                 // 4.8 MB
    int2* tdesc = (int2*)alloc((size_t)NTILE_MAX * 8);                    // 1.4 MB
    int* row_st = (int*)alloc((size_t)(N_NODES + 1) * 4);
    float* inv_deg = (float*)alloc((size_t)N_NODES * 4);
    float* T = (float*)alloc((size_t)NATOM * GC * 4);
    int* bsums = (int*)alloc(512 * 4);
    int* boffs = (int*)alloc(512 * 4);
    const size_t ZR_INTS = (size_t)2 * N_NODES + 128 * NLAYERS + 64;
    char* zr = alloc(ZR_INTS * 4);
    int* deg = (int*)zr;
    int* cursor = deg + N_NODES;
    float* stats = (float*)(cursor + N_NODES);
    int* tcount = (int*)(stats + 128 * NLAYERS);

    if ((size_t)(p - base) > ws_size) return;  // diagnostic bail

    hipMemsetAsync(zr, 0, ZR_INTS * 4, stream);

    const int EG = (N_EDGES + 255) / 256;
    deg_kernel<<<EG, 256, 0, stream>>>(edge_index, deg);
    scan_a_kernel<<<391, 256, 0, stream>>>(deg, bsums);
    scan_b_kernel<<<1, 512, 0, stream>>>(bsums, boffs);
    scan_c_kernel<<<391, 256, 0, stream>>>(deg, boffs, row_st, inv_deg, tdesc, tcount);
    scatter_kernel<<<EG, 256, 0, stream>>>(edge_index, pos, row_st, cursor, csr_src, csr_dist);
    rbf_kernel<<<EG, 256, 0, stream>>>(csr_dist, means, betas, ea);
    atom_table_kernel<<<NATOM, 64, 0, stream>>>(emb, pre_W, pre_b, T);
    xinit_kernel<<<N_NODES * 16 / 256, 256, 0, stream>>>(atom_types, T, x, x16);
    proj_kernel<<<N_NODES / 32, 256, 0, stream>>>(x16, Wf, Ws, P2);

    for (int l = 0; l < NLAYERS; l++) {
        const float* Wfl = Wf + (size_t)l * 160 * GC;
        const float* Wsl = Ws + (size_t)l * 160 * GC;
        tile_mfma_kernel<<<TILE_GRID, 256, 0, stream>>>(
            x16, (const _Float16*)ea, csr_src, tdesc, tcount, inv_deg, P2,
            Wfl, Wsl, bf + l * GC, bs + l * GC, x);
        stats_kernel<<<256, 256, 0, stream>>>(x, stats + l * 128);
        if (l < NLAYERS - 1) {
            bnproj_kernel<<<N_NODES / 32, 256, 0, stream>>>(
                x, stats + l * 128, gamma + l * GC, beta + l * GC,
                x, x16, Wfl + 160 * GC, Wsl + 160 * GC, P2);
        } else {
            bn_kernel<<<N_NODES * 16 / 256, 256, 0, stream>>>(
                x, stats + l * 128, gamma + l * GC, beta + l * GC, (float*)d_out);
        }
    }
}